// Round 2
// baseline (691.988 us; speedup 1.0000x reference)
//
#include <hip/hip_runtime.h>

#define HID 16
#define NFEAT 512

// ---------------------------------------------------------------- CSR build
__global__ __launch_bounds__(256) void deg_count_int(const int* __restrict__ dst,
                                                     int* __restrict__ ideg, int e) {
    int i = blockIdx.x * 256 + threadIdx.x;
    if (i < e) atomicAdd(&ideg[dst[i]], 1);
}

// per-256-block exclusive scan (Hillis-Steele), emits block sums
__global__ __launch_bounds__(256) void scan1(const int* __restrict__ ideg,
                                             int* __restrict__ off,
                                             int* __restrict__ bsum, int n) {
    __shared__ int s[256];
    int i = blockIdx.x * 256 + threadIdx.x;
    int v = (i < n) ? ideg[i] : 0;
    s[threadIdx.x] = v;
    __syncthreads();
    for (int d = 1; d < 256; d <<= 1) {
        int t = (threadIdx.x >= d) ? s[threadIdx.x - d] : 0;
        __syncthreads();
        s[threadIdx.x] += t;
        __syncthreads();
    }
    if (i < n) off[i] = s[threadIdx.x] - v;            // exclusive within block
    if (threadIdx.x == 255) bsum[blockIdx.x] = s[255]; // block total
}

// single-block exclusive scan of block sums (nb <= 512)
__global__ __launch_bounds__(512) void scan2(int* __restrict__ bsum, int nb) {
    __shared__ int s[512];
    int v = (threadIdx.x < nb) ? bsum[threadIdx.x] : 0;
    s[threadIdx.x] = v;
    __syncthreads();
    for (int d = 1; d < 512; d <<= 1) {
        int t = (threadIdx.x >= d) ? s[threadIdx.x - d] : 0;
        __syncthreads();
        s[threadIdx.x] += t;
        __syncthreads();
    }
    if (threadIdx.x < nb) bsum[threadIdx.x] = s[threadIdx.x] - v;
}

__global__ __launch_bounds__(256) void finalize_off(int* __restrict__ off,
                                                    const int* __restrict__ bsum,
                                                    const int* __restrict__ ideg,
                                                    float* __restrict__ dis,
                                                    int* __restrict__ cur, int n, int e) {
    int i = blockIdx.x * 256 + threadIdx.x;
    if (i < n) {
        int o = off[i] + bsum[i >> 8];
        off[i] = o;
        cur[i] = o;
        dis[i] = rsqrtf(1.0f + (float)ideg[i]);
    }
    if (i == 0) off[n] = e;
}

__global__ __launch_bounds__(256) void scatter_csr(const int* __restrict__ src,
                                                   const int* __restrict__ dst,
                                                   int* __restrict__ cur,
                                                   int* __restrict__ csr, int e) {
    int i = blockIdx.x * 256 + threadIdx.x;
    if (i < e) {
        int p = atomicAdd(&cur[dst[i]], 1);
        csr[p] = src[i];
    }
}

// ---------------------------------------------------------------- h1 = x @ W1
// Block = 256 thr = 16 rows x 16 k-chunks. W1 staged TRANSPOSED in LDS so each
// lane reads W1t[j][k..k+3] as a conflict-free ds_read_b128. x loads: lane
// (r,c) reads float4 at row*512 + i*64 + c*4 -> 4 x 256B contiguous segments
// per wave instruction (coalesced). 16-way partial reduction via padded LDS.
__global__ __launch_bounds__(256) void mm1(const float* __restrict__ x,
                                           const float* __restrict__ W1,
                                           float* __restrict__ h1, int n) {
    __shared__ float lds[NFEAT * HID];        // 32 KB: W1t, then reused as red[]
    float* W1t = lds;                         // [16][512]
    // stage W1 transposed, coalesced global reads
    for (int idx = threadIdx.x; idx < NFEAT * HID / 4; idx += 256) {
        int k = idx >> 2, j0 = (idx & 3) * 4;
        float4 v = ((const float4*)W1)[idx];
        W1t[(j0 + 0) * NFEAT + k] = v.x;
        W1t[(j0 + 1) * NFEAT + k] = v.y;
        W1t[(j0 + 2) * NFEAT + k] = v.z;
        W1t[(j0 + 3) * NFEAT + k] = v.w;
    }
    __syncthreads();

    int r = threadIdx.x >> 4;                 // row within block
    int c = threadIdx.x & 15;                 // k-chunk
    int row = blockIdx.x * 16 + r;
    bool active = (row < n);

    float acc[HID];
#pragma unroll
    for (int j = 0; j < HID; ++j) acc[j] = 0.f;

    if (active) {
        const float4* xr = (const float4*)x + (size_t)row * (NFEAT / 4);
#pragma unroll
        for (int i = 0; i < 8; ++i) {
            float4 xv = xr[i * 16 + c];
            int kb = i * 64 + c * 4;
#pragma unroll
            for (int j = 0; j < HID; ++j) {
                float4 w = *(const float4*)&W1t[j * NFEAT + kb];
                acc[j] += xv.x * w.x + xv.y * w.y + xv.z * w.z + xv.w * w.w;
            }
        }
    }
    __syncthreads();   // done with W1t; reuse lds as red[16][16][17]

    float* red = lds;
#pragma unroll
    for (int j = 0; j < HID; ++j)
        red[r * 272 + c * 17 + j] = acc[j];
    __syncthreads();

    // thread (r, j=c) sums over the 16 chunks
    float sum = 0.f;
#pragma unroll
    for (int cc = 0; cc < 16; ++cc)
        sum += red[r * 272 + cc * 17 + c];
    if (active)
        h1[(size_t)blockIdx.x * 256 + threadIdx.x] = sum;
}

// ------------------------------------------------- aggregation via CSR (no atomics)
// out[v][j] = dis[v] * sum_{s in N(v)} h[s][j] * dis[s]     (self term added later)
__global__ __launch_bounds__(256) void agg_csr(const int* __restrict__ off,
                                               const int* __restrict__ csr,
                                               const float* __restrict__ dis,
                                               const float* __restrict__ h,
                                               float* __restrict__ out, int n) {
    int idx = blockIdx.x * 256 + threadIdx.x;
    int v = idx >> 4, j = idx & 15;
    if (v >= n) return;
    int b = off[v], en = off[v + 1];
    float acc = 0.f;
    for (int e = b; e < en; ++e) {
        int s = csr[e];
        acc += h[(size_t)s * HID + j] * dis[s];
    }
    out[idx] = acc * dis[v];
}

// ---------------------------------------------------------------- fused middle
// h = relu(agg1 + h1*dis^2 + b1);  h2 = h @ W2 (intra-16-lane shuffles); h2 -> h1
__global__ __launch_bounds__(256) void mid(const float* __restrict__ agg1,
                                           float* __restrict__ h1,
                                           const float* __restrict__ dis,
                                           const float* __restrict__ b1,
                                           const float* __restrict__ W2, int n) {
    __shared__ float W2s[HID * HID];
    if (threadIdx.x < HID * HID) W2s[threadIdx.x] = W2[threadIdx.x];
    __syncthreads();

    int idx = blockIdx.x * 256 + threadIdx.x;
    int nrow = idx >> 4, j = idx & 15;
    if (nrow >= n) return;
    float dn = dis[nrow];
    float a = agg1[idx] + h1[idx] * dn * dn + b1[j];
    float hv = fmaxf(a, 0.f);
    float h2 = 0.f;
#pragma unroll
    for (int k = 0; k < HID; ++k)
        h2 += __shfl(hv, k, HID) * W2s[k * HID + j];
    h1[idx] = h2;
}

// z = agg2 + h2*dis^2 + b2;  out = z + eps*exp(0.5*z)
__global__ __launch_bounds__(256) void finalk(float* __restrict__ out,
                                              const float* __restrict__ h2,
                                              const float* __restrict__ dis,
                                              const float* __restrict__ b2,
                                              const float* __restrict__ eps, int n) {
    int idx = blockIdx.x * 256 + threadIdx.x;
    int nrow = idx >> 4, j = idx & 15;
    if (nrow >= n) return;
    float dn = dis[nrow];
    float z = out[idx] + h2[idx] * dn * dn + b2[j];
    out[idx] = z + eps[idx] * expf(0.5f * z);
}

// ---------------------------------------------------------------- fallback (atomics)
__global__ __launch_bounds__(256) void init_deg(float* deg, int n) {
    int i = blockIdx.x * 256 + threadIdx.x;
    if (i < n) deg[i] = 1.0f;
}
__global__ __launch_bounds__(256) void deg_count_f(const int* __restrict__ dst, float* deg, int e) {
    int i = blockIdx.x * 256 + threadIdx.x;
    if (i < e) atomicAdd(&deg[dst[i]], 1.0f);
}
__global__ __launch_bounds__(256) void deg_rsqrt(float* deg, int n) {
    int i = blockIdx.x * 256 + threadIdx.x;
    if (i < n) deg[i] = rsqrtf(deg[i]);
}
__global__ __launch_bounds__(256) void prop_atomic(const int* __restrict__ src,
                                                   const int* __restrict__ dst,
                                                   const float* __restrict__ dis,
                                                   const float* __restrict__ h,
                                                   float* __restrict__ agg, int e) {
    int idx = blockIdx.x * 256 + threadIdx.x;
    int ed = idx >> 4, j = idx & 15;
    if (ed >= e) return;
    int s = src[ed], d = dst[ed];
    float w = dis[s] * dis[d];
    atomicAdd(&agg[(size_t)d * HID + j], h[(size_t)s * HID + j] * w);
}

extern "C" void kernel_launch(void* const* d_in, const int* in_sizes, int n_in,
                              void* d_out, int out_size, void* d_ws, size_t ws_size,
                              hipStream_t stream) {
    const float* x   = (const float*)d_in[0];
    const float* W1  = (const float*)d_in[1];
    const float* b1  = (const float*)d_in[2];
    const float* W2  = (const float*)d_in[3];
    const float* b2  = (const float*)d_in[4];
    const float* eps = (const float*)d_in[5];
    const int*   ei  = (const int*)d_in[6];

    int n = in_sizes[5] / HID;   // 100000
    int e = in_sizes[6] / 2;     // 3200000
    const int* srcs = ei;
    const int* dsts = ei + e;

    int nBlk    = (n + 255) / 256;           // 391
    int eBlk    = (e + 255) / 256;           // 12500
    int rowBlk  = (n + 15) / 16;             // 6250
    int featBlk = (n * 16 + 255) / 256;      // 6250
    float* outf = (float*)d_out;

    // CSR-path workspace layout (floats/ints, 4B each)
    // [dis n][ideg n][off n+1][cur n][bsum 512][csr e][h1 n*16][agg1 n*16]
    size_t needElems = (size_t)n * 4 + 1 + 512 + (size_t)e + (size_t)n * HID * 2;
    bool csrPath = (ws_size >= needElems * sizeof(float));

    if (csrPath) {
        float* dis  = (float*)d_ws;
        int*   ideg = (int*)(dis + n);
        int*   off  = ideg + n;
        int*   cur  = off + n + 1;
        int*   bsum = cur + n;
        int*   csr  = bsum + 512;
        float* h1   = (float*)(csr + e);
        float* agg1 = h1 + (size_t)n * HID;

        hipMemsetAsync(ideg, 0, (size_t)n * sizeof(int), stream);
        deg_count_int<<<eBlk, 256, 0, stream>>>(dsts, ideg, e);
        scan1<<<nBlk, 256, 0, stream>>>(ideg, off, bsum, n);
        scan2<<<1, 512, 0, stream>>>(bsum, nBlk);
        finalize_off<<<nBlk, 256, 0, stream>>>(off, bsum, ideg, dis, cur, n, e);
        scatter_csr<<<eBlk, 256, 0, stream>>>(srcs, dsts, cur, csr, e);

        mm1<<<rowBlk, 256, 0, stream>>>(x, W1, h1, n);
        agg_csr<<<featBlk, 256, 0, stream>>>(off, csr, dis, h1, agg1, n);
        mid<<<featBlk, 256, 0, stream>>>(agg1, h1, dis, b1, W2, n);
        agg_csr<<<featBlk, 256, 0, stream>>>(off, csr, dis, h1, outf, n);
        finalk<<<featBlk, 256, 0, stream>>>(outf, h1, dis, b2, eps, n);
    } else {
        // fallback: atomic scatter (round-1 path)
        float* dis  = (float*)d_ws;
        float* h1   = dis + n;
        float* agg1 = h1 + (size_t)n * HID;
        size_t featBytes = (size_t)n * HID * sizeof(float);

        hipMemsetAsync(agg1, 0, featBytes, stream);
        hipMemsetAsync(outf, 0, featBytes, stream);
        init_deg<<<nBlk, 256, 0, stream>>>(dis, n);
        deg_count_f<<<eBlk, 256, 0, stream>>>(dsts, dis, e);
        deg_rsqrt<<<nBlk, 256, 0, stream>>>(dis, n);

        mm1<<<rowBlk, 256, 0, stream>>>(x, W1, h1, n);
        int propBlocks = (e * 16 + 255) / 256;
        prop_atomic<<<propBlocks, 256, 0, stream>>>(srcs, dsts, dis, h1, agg1, e);
        mid<<<featBlk, 256, 0, stream>>>(agg1, h1, dis, b1, W2, n);
        prop_atomic<<<propBlocks, 256, 0, stream>>>(srcs, dsts, dis, h1, outf, e);
        finalk<<<featBlk, 256, 0, stream>>>(outf, h1, dis, b2, eps, n);
    }
}